// Round 6
// baseline (166.962 us; speedup 1.0000x reference)
//
#include <hip/hip_runtime.h>

#define RAD 8
#define HH 256
#define WW 256
#define NC 12           // n*c planes
#define PS (HH*WW)      // plane size

// ---------- K1: horizontal box (17-tap clamped) of 6 products + per-block partial sums ----------
// grid: NC*64 blocks (4 rows/block), 256 threads (one per column)
__global__ __launch_bounds__(256) void k_hbox6(const float* __restrict__ la,
                                               const float* __restrict__ lx,
                                               const float* __restrict__ ly,
                                               float* __restrict__ Hbuf,
                                               float* __restrict__ partials) {
    int p  = blockIdx.x >> 6;
    int rc = blockIdx.x & 63;
    int base = p * PS + rc * 4 * WW;
    int tid = threadIdx.x, lane = tid & 63, wid = tid >> 6;
    __shared__ float wtot[6][4];
    __shared__ float Pref[6][WW];
    __shared__ float ls[4];
    float asum = 0.0f;
    int  j1    = min(tid + RAD, WW - 1);
    bool hasj0 = (tid - RAD) > 0;
    int  j0m1  = tid - RAD - 1;
    for (int rr = 0; rr < 4; rr++) {
        int o = base + rr * WW + tid;
        float a  = fabsf(la[o]) + 1e-12f;
        float xv = lx[o];
        float yv = ly[o];
        asum += a;
        float ax = a * xv, ay = a * yv;
        float v0 = a, v1 = ax, v2 = ay, v3 = a * ax, v4 = ax * ax, v5 = ax * ay;
        #pragma unroll
        for (int off = 1; off < 64; off <<= 1) {
            float t0 = __shfl_up(v0, off, 64), t1 = __shfl_up(v1, off, 64),
                  t2 = __shfl_up(v2, off, 64), t3 = __shfl_up(v3, off, 64),
                  t4 = __shfl_up(v4, off, 64), t5 = __shfl_up(v5, off, 64);
            if (lane >= off) { v0 += t0; v1 += t1; v2 += t2; v3 += t3; v4 += t4; v5 += t5; }
        }
        if (lane == 63) {
            wtot[0][wid] = v0; wtot[1][wid] = v1; wtot[2][wid] = v2;
            wtot[3][wid] = v3; wtot[4][wid] = v4; wtot[5][wid] = v5;
        }
        __syncthreads();
        float a0 = 0, a1 = 0, a2 = 0, a3 = 0, a4 = 0, a5 = 0;
        for (int w = 0; w < wid; w++) {
            a0 += wtot[0][w]; a1 += wtot[1][w]; a2 += wtot[2][w];
            a3 += wtot[3][w]; a4 += wtot[4][w]; a5 += wtot[5][w];
        }
        Pref[0][tid] = v0 + a0; Pref[1][tid] = v1 + a1; Pref[2][tid] = v2 + a2;
        Pref[3][tid] = v3 + a3; Pref[4][tid] = v4 + a4; Pref[5][tid] = v5 + a5;
        __syncthreads();
        #pragma unroll
        for (int k = 0; k < 6; k++) {
            float s = Pref[k][j1] - (hasj0 ? Pref[k][j0m1] : 0.0f);
            Hbuf[k * NC * PS + o] = s;
        }
    }
    for (int off = 32; off > 0; off >>= 1) asum += __shfl_down(asum, off, 64);
    if (lane == 0) ls[wid] = asum;
    __syncthreads();
    if (tid == 0) partials[blockIdx.x] = ls[0] + ls[1] + ls[2] + ls[3];
}

// ---------- K2: fused vertical box + A,b + horizontal box + second vertical box ----------
// grid: NC*64 blocks (4 output rows each), 256 threads (one per column).
// Computes A/b rows [i0-8, i0+11] (<=20) barrier-free into LDS, wave-per-row scan,
// prefix-diff + predicated static window sums -> mA,mB. 3 barriers total.
__global__ __launch_bounds__(256) void k_vabf(const float* __restrict__ Hbuf,
                                              const float* __restrict__ partials,
                                              float* __restrict__ mA,
                                              float* __restrict__ mB) {
    int p  = blockIdx.x >> 6;
    int i0 = (blockIdx.x & 63) * 4;
    int tid = threadIdx.x, lane = tid & 63, wid = tid >> 6;
    __shared__ float AvB[20][WW];
    __shared__ float BvB[20][WW];
    __shared__ float ls[4];
    __shared__ float sS;

    // reduce the 768 per-block partials -> invS
    float psum = partials[tid] + partials[tid + 256] + partials[tid + 512];
    for (int off = 32; off > 0; off >>= 1) psum += __shfl_down(psum, off, 64);
    if (lane == 0) ls[wid] = psum;
    __syncthreads();
    if (tid == 0) sS = ls[0] + ls[1] + ls[2] + ls[3];
    __syncthreads();
    float invS = 1.0f / sS;

    int jA0 = max(i0 - RAD, 0);
    int jA1 = min(i0 + 4 + RAD - 1, HH - 1);    // i0+11
    int nrows = jA1 - jA0 + 1;                  // <= 20, block-uniform

    float cx = (float)(min(tid + RAD, WW - 1) - max(tid - RAD, 0) + 1);

    // ---- Stage 1: A/b rows jA0..jA1, per-thread vertical sliding (no barriers) ----
    {
        const float* Hp = Hbuf + p * PS + tid;
        float s0 = 0, s1 = 0, s2 = 0, s3 = 0, s4 = 0, s5 = 0;
        int lo0 = max(jA0 - RAD, 0), hi0 = min(jA0 + RAD, HH - 1);
        for (int i = lo0; i <= hi0; i++) {
            int o = i * WW;
            s0 += Hp[0 * NC * PS + o]; s1 += Hp[1 * NC * PS + o]; s2 += Hp[2 * NC * PS + o];
            s3 += Hp[3 * NC * PS + o]; s4 += Hp[4 * NC * PS + o]; s5 += Hp[5 * NC * PS + o];
        }
        for (int jj = 0; jj < nrows; jj++) {
            int j = jA0 + jj;
            if (jj > 0) {
                int add = j + RAD, sub = j - RAD - 1;
                if (add <= HH - 1) {
                    int o = add * WW;
                    s0 += Hp[0 * NC * PS + o]; s1 += Hp[1 * NC * PS + o]; s2 += Hp[2 * NC * PS + o];
                    s3 += Hp[3 * NC * PS + o]; s4 += Hp[4 * NC * PS + o]; s5 += Hp[5 * NC * PS + o];
                }
                if (sub >= 0) {
                    int o = sub * WW;
                    s0 -= Hp[0 * NC * PS + o]; s1 -= Hp[1 * NC * PS + o]; s2 -= Hp[2 * NC * PS + o];
                    s3 -= Hp[3 * NC * PS + o]; s4 -= Hp[4 * NC * PS + o]; s5 -= Hp[5 * NC * PS + o];
                }
            }
            float cy = (float)(min(j + RAD, HH - 1) - max(j - RAD, 0) + 1);
            float Nv = cx * cy;
            float invN = 1.0f / Nv;
            float mean_a    = s0 * invN;
            float mean_ax   = s1 * invN;
            float mean_ay   = s2 * invN;
            float mean_tax  = s3 * invN * invS;
            float mean_a2x2 = s4 * invN;
            float mean_a2xy = s5 * invN;
            float temp = fabsf(mean_a2x2 - Nv * mean_tax * mean_ax);
            float Av = (mean_a2xy - Nv * mean_tax * mean_ay) / (temp + 1e-8f);
            float bv = (mean_ay - Av * mean_ax) / mean_a;
            AvB[jj][tid] = Av;
            BvB[jj][tid] = bv;
        }
    }
    __syncthreads();

    // ---- Stage 2: in-place inclusive prefix per row; each wave owns rows wid, wid+4, ... ----
    for (int r = wid; r < nrows; r += 4) {
        float4 va = *(float4*)&AvB[r][lane << 2];
        va.y += va.x; va.z += va.y; va.w += va.z;
        float tot = va.w;
        #pragma unroll
        for (int off = 1; off < 64; off <<= 1) {
            float t = __shfl_up(tot, off, 64);
            if (lane >= off) tot += t;
        }
        float excl = tot - va.w;
        va.x += excl; va.y += excl; va.z += excl; va.w += excl;
        *(float4*)&AvB[r][lane << 2] = va;

        float4 vb = *(float4*)&BvB[r][lane << 2];
        vb.y += vb.x; vb.z += vb.y; vb.w += vb.z;
        float tot2 = vb.w;
        #pragma unroll
        for (int off = 1; off < 64; off <<= 1) {
            float t = __shfl_up(tot2, off, 64);
            if (lane >= off) tot2 += t;
        }
        float excl2 = tot2 - vb.w;
        vb.x += excl2; vb.y += excl2; vb.z += excl2; vb.w += excl2;
        *(float4*)&BvB[r][lane << 2] = vb;
    }
    __syncthreads();

    // ---- Stage 3: prefix-diff -> HA/HB; predicated window sums for the 4 outputs ----
    int  j1c   = min(tid + RAD, WW - 1);
    bool hasj0 = (tid - RAD) > 0;
    int  j0m1  = tid - RAD - 1;
    int lo0 = max(i0 + 0 - RAD, 0) - jA0, hi0 = min(i0 + 0 + RAD, HH - 1) - jA0;
    int lo1 = max(i0 + 1 - RAD, 0) - jA0, hi1 = min(i0 + 1 + RAD, HH - 1) - jA0;
    int lo2 = max(i0 + 2 - RAD, 0) - jA0, hi2 = min(i0 + 2 + RAD, HH - 1) - jA0;
    int lo3 = max(i0 + 3 - RAD, 0) - jA0, hi3 = min(i0 + 3 + RAD, HH - 1) - jA0;
    float sa0 = 0, sb0 = 0, sa1 = 0, sb1 = 0, sa2 = 0, sb2 = 0, sa3 = 0, sb3 = 0;
    #pragma unroll
    for (int jj = 0; jj < 20; jj++) {
        if (jj < nrows) {
            float ha = AvB[jj][j1c] - (hasj0 ? AvB[jj][j0m1] : 0.0f);
            float hb = BvB[jj][j1c] - (hasj0 ? BvB[jj][j0m1] : 0.0f);
            if (jj >= lo0 && jj <= hi0) { sa0 += ha; sb0 += hb; }
            if (jj >= lo1 && jj <= hi1) { sa1 += ha; sb1 += hb; }
            if (jj >= lo2 && jj <= hi2) { sa2 += ha; sb2 += hb; }
            if (jj >= lo3 && jj <= hi3) { sa3 += ha; sb3 += hb; }
        }
    }
    #pragma unroll
    for (int k = 0; k < 4; k++) {
        int r = i0 + k;
        float cy2 = (float)(min(r + RAD, HH - 1) - max(r - RAD, 0) + 1);
        float inv = 1.0f / (cx * cy2);
        float sa = (k == 0) ? sa0 : (k == 1) ? sa1 : (k == 2) ? sa2 : sa3;
        float sb = (k == 0) ? sb0 : (k == 1) ? sb1 : (k == 2) ? sb2 : sb3;
        mA[p * PS + r * WW + tid] = sa * inv;
        mB[p * PS + r * WW + tid] = sb * inv;
    }
}

// ---------- K3: bilinear upsample + fuse with hr_x ----------
__global__ __launch_bounds__(256) void k_resize(const float* __restrict__ mA,
                                                const float* __restrict__ mB,
                                                const float* __restrict__ hrx,
                                                float* __restrict__ out) {
    int idx = blockIdx.x * 256 + threadIdx.x;   // float4 index
    int p   = idx >> 18;                        // 1024*256 float4 per plane
    int rem = idx & ((1 << 18) - 1);
    int I   = rem >> 8;                         // HR row
    int J4  = (rem & 255) << 2;                 // HR col start
    const float scale = 255.0f / 1023.0f;
    float ysf = (float)I * scale;
    int   y0  = (int)ysf;
    float wy  = ysf - (float)y0;
    int   y1  = min(y0 + 1, HH - 1);
    const float* a0p = mA + p * PS + y0 * WW;
    const float* a1p = mA + p * PS + y1 * WW;
    const float* b0p = mB + p * PS + y0 * WW;
    const float* b1p = mB + p * PS + y1 * WW;
    int xb = (int)((float)J4 * scale);
    int i1 = min(xb + 1, WW - 1);
    int i2 = min(xb + 2, WW - 1);
    float A0a = a0p[xb], A0b = a0p[i1], A0c = a0p[i2];
    float A1a = a1p[xb], A1b = a1p[i1], A1c = a1p[i2];
    float B0a = b0p[xb], B0b = b0p[i1], B0c = b0p[i2];
    float B1a = b1p[xb], B1b = b1p[i1], B1c = b1p[i2];
    float4 h = ((const float4*)hrx)[idx];
    float hv[4] = {h.x, h.y, h.z, h.w};
    float ov[4];
    float omwy = 1.0f - wy;
    #pragma unroll
    for (int k = 0; k < 4; k++) {
        float xsk = (float)(J4 + k) * scale;
        int   x0  = (int)xsk;
        float wx  = xsk - (float)x0;
        bool hisel = (x0 > xb);
        float Alo0 = hisel ? A0b : A0a, Ahi0 = hisel ? A0c : A0b;
        float Alo1 = hisel ? A1b : A1a, Ahi1 = hisel ? A1c : A1b;
        float Blo0 = hisel ? B0b : B0a, Bhi0 = hisel ? B0c : B0b;
        float Blo1 = hisel ? B1b : B1a, Bhi1 = hisel ? B1c : B1b;
        float omwx = 1.0f - wx;
        float Ar0 = Alo0 * omwx + Ahi0 * wx;
        float Ar1 = Alo1 * omwx + Ahi1 * wx;
        float Br0 = Blo0 * omwx + Bhi0 * wx;
        float Br1 = Blo1 * omwx + Bhi1 * wx;
        float Avv = Ar0 * omwy + Ar1 * wy;
        float Bvv = Br0 * omwy + Br1 * wy;
        ov[k] = Avv * hv[k] + Bvv;
    }
    float4 o;
    o.x = ov[0]; o.y = ov[1]; o.z = ov[2]; o.w = ov[3];
    ((float4*)out)[idx] = o;
}

extern "C" void kernel_launch(void* const* d_in, const int* in_sizes, int n_in,
                              void* d_out, int out_size, void* d_ws, size_t ws_size,
                              hipStream_t stream) {
    const float* lr_x = (const float*)d_in[0];
    const float* lr_y = (const float*)d_in[1];
    const float* hr_x = (const float*)d_in[2];
    const float* l_a  = (const float*)d_in[3];
    float* out = (float*)d_out;

    // workspace layout (floats): partials[1024] | Hbuf[6 planes] | mA | mB
    float* ws       = (float*)d_ws;
    float* partials = ws;
    float* Hbuf     = ws + 1024;
    float* mA       = Hbuf + 6 * NC * PS;
    float* mB       = mA + NC * PS;

    k_hbox6 <<<NC * 64, 256, 0, stream>>>(l_a, lr_x, lr_y, Hbuf, partials);
    k_vabf  <<<NC * 64, 256, 0, stream>>>(Hbuf, partials, mA, mB);
    k_resize<<<(NC * 1024 * 1024 / 4) / 256, 256, 0, stream>>>(mA, mB, hr_x, out);
}

// Round 7
// 151.434 us; speedup vs baseline: 1.1025x; 1.1025x over previous
//
#include <hip/hip_runtime.h>

#define RAD 8
#define HH 256
#define WW 256
#define NC 12           // n*c planes
#define PS (HH*WW)      // plane size

// XCD-consistent swizzle: 768 blocks, XCD = b%8 (round-robin heuristic).
// chunk c = (b&7)*96 + (b>>3) gives each XCD 96 CONTIGUOUS row-chunks, so a
// chunk's writer (k_hbox6) and its +/-2-chunk readers (k_vab/k_vbox2) share an XCD L2.
__device__ __forceinline__ int swz(int b) { return (b & 7) * 96 + (b >> 3); }

// ---------- K1: horizontal box (17-tap clamped) of 6 products + per-block partial sums ----------
// grid: NC*64 blocks (4 rows/block), 256 threads (one per column)
__global__ __launch_bounds__(256) void k_hbox6(const float* __restrict__ la,
                                               const float* __restrict__ lx,
                                               const float* __restrict__ ly,
                                               float* __restrict__ Hbuf,
                                               float* __restrict__ partials) {
    int c  = swz(blockIdx.x);
    int p  = c >> 6;
    int rc = c & 63;
    int base = p * PS + rc * 4 * WW;
    int tid = threadIdx.x, lane = tid & 63, wid = tid >> 6;
    __shared__ float wtot[6][4];
    __shared__ float Pref[6][WW];
    __shared__ float ls[4];
    float asum = 0.0f;
    int  j1    = min(tid + RAD, WW - 1);
    bool hasj0 = (tid - RAD) > 0;
    int  j0m1  = tid - RAD - 1;
    for (int rr = 0; rr < 4; rr++) {
        int o = base + rr * WW + tid;
        float a  = fabsf(la[o]) + 1e-12f;
        float xv = lx[o];
        float yv = ly[o];
        asum += a;
        float ax = a * xv, ay = a * yv;
        float v0 = a, v1 = ax, v2 = ay, v3 = a * ax, v4 = ax * ax, v5 = ax * ay;
        #pragma unroll
        for (int off = 1; off < 64; off <<= 1) {
            float t0 = __shfl_up(v0, off, 64), t1 = __shfl_up(v1, off, 64),
                  t2 = __shfl_up(v2, off, 64), t3 = __shfl_up(v3, off, 64),
                  t4 = __shfl_up(v4, off, 64), t5 = __shfl_up(v5, off, 64);
            if (lane >= off) { v0 += t0; v1 += t1; v2 += t2; v3 += t3; v4 += t4; v5 += t5; }
        }
        if (lane == 63) {
            wtot[0][wid] = v0; wtot[1][wid] = v1; wtot[2][wid] = v2;
            wtot[3][wid] = v3; wtot[4][wid] = v4; wtot[5][wid] = v5;
        }
        __syncthreads();
        float a0 = 0, a1 = 0, a2 = 0, a3 = 0, a4 = 0, a5 = 0;
        for (int w = 0; w < wid; w++) {
            a0 += wtot[0][w]; a1 += wtot[1][w]; a2 += wtot[2][w];
            a3 += wtot[3][w]; a4 += wtot[4][w]; a5 += wtot[5][w];
        }
        Pref[0][tid] = v0 + a0; Pref[1][tid] = v1 + a1; Pref[2][tid] = v2 + a2;
        Pref[3][tid] = v3 + a3; Pref[4][tid] = v4 + a4; Pref[5][tid] = v5 + a5;
        __syncthreads();
        #pragma unroll
        for (int k = 0; k < 6; k++) {
            float s = Pref[k][j1] - (hasj0 ? Pref[k][j0m1] : 0.0f);
            Hbuf[k * NC * PS + o] = s;
        }
    }
    for (int off = 32; off > 0; off >>= 1) asum += __shfl_down(asum, off, 64);
    if (lane == 0) ls[wid] = asum;
    __syncthreads();
    if (tid == 0) partials[blockIdx.x] = ls[0] + ls[1] + ls[2] + ls[3];
}

// ---------- K2: vertical box + pointwise A,b + horizontal box of A,b (4 rows/block) ----------
// grid: NC*64 blocks, 256 threads
__global__ __launch_bounds__(256) void k_vab(const float* __restrict__ Hbuf,
                                             const float* __restrict__ partials,
                                             float* __restrict__ HA,
                                             float* __restrict__ HB) {
    int c  = swz(blockIdx.x);
    int p  = c >> 6;
    int i0 = (c & 63) * 4;
    int tid = threadIdx.x, lane = tid & 63, wid = tid >> 6;
    __shared__ float wtot[2][4];
    __shared__ float Pref[2][WW];
    __shared__ float ls[4];
    __shared__ float sS;

    // reduce the 768 per-block partials -> invS
    float psum = partials[tid] + partials[tid + 256] + partials[tid + 512];
    for (int off = 32; off > 0; off >>= 1) psum += __shfl_down(psum, off, 64);
    if (lane == 0) ls[wid] = psum;
    __syncthreads();
    if (tid == 0) sS = ls[0] + ls[1] + ls[2] + ls[3];
    __syncthreads();
    float invS = 1.0f / sS;

    const float* Hp = Hbuf + p * PS + tid;
    float s0 = 0, s1 = 0, s2 = 0, s3 = 0, s4 = 0, s5 = 0;
    int lo = max(i0 - RAD, 0), hi = min(i0 + RAD, HH - 1);
    for (int i = lo; i <= hi; i++) {
        int o = i * WW;
        s0 += Hp[0 * NC * PS + o]; s1 += Hp[1 * NC * PS + o]; s2 += Hp[2 * NC * PS + o];
        s3 += Hp[3 * NC * PS + o]; s4 += Hp[4 * NC * PS + o]; s5 += Hp[5 * NC * PS + o];
    }
    float cx = (float)(min(tid + RAD, WW - 1) - max(tid - RAD, 0) + 1);
    int  j1c   = min(tid + RAD, WW - 1);
    bool hasj0 = (tid - RAD) > 0;
    int  j0m1  = tid - RAD - 1;
    for (int i = i0; i < i0 + 4; i++) {
        if (i > i0) {
            int add = i + RAD, sub = i - RAD - 1;
            if (add <= HH - 1) {
                int o = add * WW;
                s0 += Hp[0 * NC * PS + o]; s1 += Hp[1 * NC * PS + o]; s2 += Hp[2 * NC * PS + o];
                s3 += Hp[3 * NC * PS + o]; s4 += Hp[4 * NC * PS + o]; s5 += Hp[5 * NC * PS + o];
            }
            if (sub >= 0) {
                int o = sub * WW;
                s0 -= Hp[0 * NC * PS + o]; s1 -= Hp[1 * NC * PS + o]; s2 -= Hp[2 * NC * PS + o];
                s3 -= Hp[3 * NC * PS + o]; s4 -= Hp[4 * NC * PS + o]; s5 -= Hp[5 * NC * PS + o];
            }
        }
        float cy = (float)(min(i + RAD, HH - 1) - max(i - RAD, 0) + 1);
        float Nv = cx * cy;
        float invN = 1.0f / Nv;
        float mean_a    = s0 * invN;
        float mean_ax   = s1 * invN;
        float mean_ay   = s2 * invN;
        float mean_tax  = s3 * invN * invS;
        float mean_a2x2 = s4 * invN;
        float mean_a2xy = s5 * invN;
        float temp = fabsf(mean_a2x2 - Nv * mean_tax * mean_ax);
        float Av = (mean_a2xy - Nv * mean_tax * mean_ay) / (temp + 1e-8f);
        float bv = (mean_ay - Av * mean_ax) / mean_a;

        float v0 = Av, v1 = bv;
        #pragma unroll
        for (int off = 1; off < 64; off <<= 1) {
            float t0 = __shfl_up(v0, off, 64), t1 = __shfl_up(v1, off, 64);
            if (lane >= off) { v0 += t0; v1 += t1; }
        }
        if (lane == 63) { wtot[0][wid] = v0; wtot[1][wid] = v1; }
        __syncthreads();
        float a0 = 0, a1 = 0;
        for (int w = 0; w < wid; w++) { a0 += wtot[0][w]; a1 += wtot[1][w]; }
        Pref[0][tid] = v0 + a0; Pref[1][tid] = v1 + a1;
        __syncthreads();
        int o = p * PS + i * WW + tid;
        HA[o] = Pref[0][j1c] - (hasj0 ? Pref[0][j0m1] : 0.0f);
        HB[o] = Pref[1][j1c] - (hasj0 ? Pref[1][j0m1] : 0.0f);
    }
}

// ---------- K3: vertical box of HA,HB, divide by N (4 rows/block) ----------
// grid: NC*64 blocks, 256 threads
__global__ __launch_bounds__(256) void k_vbox2(const float* __restrict__ HA,
                                               const float* __restrict__ HB,
                                               float* __restrict__ mA,
                                               float* __restrict__ mB) {
    int c  = swz(blockIdx.x);
    int p  = c >> 6;
    int i0 = (c & 63) * 4;
    int col = threadIdx.x;
    const float* a = HA + p * PS + col;
    const float* b = HB + p * PS + col;
    float sa = 0, sb = 0;
    int lo = max(i0 - RAD, 0), hi = min(i0 + RAD, HH - 1);
    for (int i = lo; i <= hi; i++) { sa += a[i * WW]; sb += b[i * WW]; }
    float cx = (float)(min(col + RAD, WW - 1) - max(col - RAD, 0) + 1);
    for (int i = i0; i < i0 + 4; i++) {
        if (i > i0) {
            if (i + RAD <= HH - 1) { sa += a[(i + RAD) * WW]; sb += b[(i + RAD) * WW]; }
            if (i - RAD - 1 >= 0)  { sa -= a[(i - RAD - 1) * WW]; sb -= b[(i - RAD - 1) * WW]; }
        }
        float cy = (float)(min(i + RAD, HH - 1) - max(i - RAD, 0) + 1);
        float inv = 1.0f / (cx * cy);
        mA[p * PS + i * WW + col] = sa * inv;
        mB[p * PS + i * WW + col] = sb * inv;
    }
}

// ---------- K4: bilinear upsample + fuse with hr_x ----------
__global__ __launch_bounds__(256) void k_resize(const float* __restrict__ mA,
                                                const float* __restrict__ mB,
                                                const float* __restrict__ hrx,
                                                float* __restrict__ out) {
    int idx = blockIdx.x * 256 + threadIdx.x;   // float4 index
    int p   = idx >> 18;                        // 1024*256 float4 per plane
    int rem = idx & ((1 << 18) - 1);
    int I   = rem >> 8;                         // HR row
    int J4  = (rem & 255) << 2;                 // HR col start
    const float scale = 255.0f / 1023.0f;
    float ysf = (float)I * scale;
    int   y0  = (int)ysf;
    float wy  = ysf - (float)y0;
    int   y1  = min(y0 + 1, HH - 1);
    const float* a0p = mA + p * PS + y0 * WW;
    const float* a1p = mA + p * PS + y1 * WW;
    const float* b0p = mB + p * PS + y0 * WW;
    const float* b1p = mB + p * PS + y1 * WW;
    int xb = (int)((float)J4 * scale);
    int i1 = min(xb + 1, WW - 1);
    int i2 = min(xb + 2, WW - 1);
    float A0a = a0p[xb], A0b = a0p[i1], A0c = a0p[i2];
    float A1a = a1p[xb], A1b = a1p[i1], A1c = a1p[i2];
    float B0a = b0p[xb], B0b = b0p[i1], B0c = b0p[i2];
    float B1a = b1p[xb], B1b = b1p[i1], B1c = b1p[i2];
    float4 h = ((const float4*)hrx)[idx];
    float hv[4] = {h.x, h.y, h.z, h.w};
    float ov[4];
    float omwy = 1.0f - wy;
    #pragma unroll
    for (int k = 0; k < 4; k++) {
        float xsk = (float)(J4 + k) * scale;
        int   x0  = (int)xsk;
        float wx  = xsk - (float)x0;
        bool hisel = (x0 > xb);
        float Alo0 = hisel ? A0b : A0a, Ahi0 = hisel ? A0c : A0b;
        float Alo1 = hisel ? A1b : A1a, Ahi1 = hisel ? A1c : A1b;
        float Blo0 = hisel ? B0b : B0a, Bhi0 = hisel ? B0c : B0b;
        float Blo1 = hisel ? B1b : B1a, Bhi1 = hisel ? B1c : B1b;
        float omwx = 1.0f - wx;
        float Ar0 = Alo0 * omwx + Ahi0 * wx;
        float Ar1 = Alo1 * omwx + Ahi1 * wx;
        float Br0 = Blo0 * omwx + Bhi0 * wx;
        float Br1 = Blo1 * omwx + Bhi1 * wx;
        float Avv = Ar0 * omwy + Ar1 * wy;
        float Bvv = Br0 * omwy + Br1 * wy;
        ov[k] = Avv * hv[k] + Bvv;
    }
    float4 o;
    o.x = ov[0]; o.y = ov[1]; o.z = ov[2]; o.w = ov[3];
    ((float4*)out)[idx] = o;
}

extern "C" void kernel_launch(void* const* d_in, const int* in_sizes, int n_in,
                              void* d_out, int out_size, void* d_ws, size_t ws_size,
                              hipStream_t stream) {
    const float* lr_x = (const float*)d_in[0];
    const float* lr_y = (const float*)d_in[1];
    const float* hr_x = (const float*)d_in[2];
    const float* l_a  = (const float*)d_in[3];
    float* out = (float*)d_out;

    // workspace layout (floats): partials[1024] | Hbuf[6 planes] | HA | HB | mA | mB
    float* ws       = (float*)d_ws;
    float* partials = ws;
    float* Hbuf     = ws + 1024;
    float* HA       = Hbuf + 6 * NC * PS;
    float* HB       = HA + NC * PS;
    float* mA       = HB + NC * PS;
    float* mB       = mA + NC * PS;

    k_hbox6 <<<NC * 64, 256, 0, stream>>>(l_a, lr_x, lr_y, Hbuf, partials);
    k_vab   <<<NC * 64, 256, 0, stream>>>(Hbuf, partials, HA, HB);
    k_vbox2 <<<NC * 64, 256, 0, stream>>>(HA, HB, mA, mB);
    k_resize<<<(NC * 1024 * 1024 / 4) / 256, 256, 0, stream>>>(mA, mB, hr_x, out);
}